// Round 6
// baseline (184.269 us; speedup 1.0000x reference)
//
#include <hip/hip_runtime.h>

#define NC 20
#define CH 30

constexpr int TPB = 256;         // 4 waves/block
constexpr int NBLOCKS = 2048;    // grid-stride; scheduler keeps ~4 blocks/CU resident

// Per-cell YOLOv1 loss (validated rounds 1-5, absmax 0.0). Reads 8B-aligned
// global memory directly: 15 dwordx2 per array, consumed by the compiler's
// own schedule. No LDS anywhere -> occupancy limited only by VGPRs.
__device__ __forceinline__ float cell_loss(const float* __restrict__ tf,
                                           const float* __restrict__ pf) {
    const float2* t2 = (const float2*)tf;
    const float2* p2 = (const float2*)pf;

    float cl = 0.f;
#pragma unroll
    for (int c = 0; c < NC / 2; ++c) {
        float2 a = t2[c], b = p2[c];
        float d0 = a.x - b.x, d1 = a.y - b.y;
        cl = fmaf(d0, d0, cl);
        cl = fmaf(d1, d1, cl);
    }
    float2 v10 = t2[10], v11 = t2[11];
    float th = t2[12].x;
    float obj = v10.x, tx = v10.y, ty = v11.x, tw = v11.y;
    float2 q10 = p2[10], q11 = p2[11], q12 = p2[12], q13 = p2[13], q14 = p2[14];
    float conf0 = q10.x, px0 = q10.y, py0 = q11.x, pw0 = q11.y, ph0 = q12.x;
    float conf1 = q12.y, px1 = q13.x, py1 = q13.y, pw1 = q14.x, ph1 = q14.y;

    float t_x1 = tx - tw * 0.5f, t_x2 = tx + tw * 0.5f;
    float t_y1 = ty - th * 0.5f, t_y2 = ty + th * 0.5f;
    float ta = fabsf((t_x2 - t_x1) * (t_y2 - t_y1));

    float b_x1 = px0 - pw0 * 0.5f, b_x2 = px0 + pw0 * 0.5f;
    float b_y1 = py0 - ph0 * 0.5f, b_y2 = py0 + ph0 * 0.5f;
    float ix = fmaxf(fminf(t_x2, b_x2) - fmaxf(t_x1, b_x1), 0.f);
    float iy = fmaxf(fminf(t_y2, b_y2) - fmaxf(t_y1, b_y1), 0.f);
    float inter0 = ix * iy;
    float a0 = fabsf((b_x2 - b_x1) * (b_y2 - b_y1));
    float iou0 = inter0 * __builtin_amdgcn_rcpf(ta + a0 - inter0 + 1e-6f);

    float c_x1 = px1 - pw1 * 0.5f, c_x2 = px1 + pw1 * 0.5f;
    float c_y1 = py1 - ph1 * 0.5f, c_y2 = py1 + ph1 * 0.5f;
    float jx = fmaxf(fminf(t_x2, c_x2) - fmaxf(t_x1, c_x1), 0.f);
    float jy = fmaxf(fminf(t_y2, c_y2) - fmaxf(t_y1, c_y1), 0.f);
    float inter1 = jx * jy;
    float a1 = fabsf((c_x2 - c_x1) * (c_y2 - c_y1));
    float iou1 = inter1 * __builtin_amdgcn_rcpf(ta + a1 - inter1 + 1e-6f);

    bool sel1 = iou1 > iou0;
    float conf = sel1 ? conf1 : conf0;
    float piou = sel1 ? iou1 : iou0;
    float px = sel1 ? px1 : px0;
    float py = sel1 ? py1 : py0;
    float pw = sel1 ? pw1 : pw0;
    float ph = sel1 ? ph1 : ph0;

    float dx = tx - px, dy = ty - py;
    float xy = dx * dx + dy * dy;
    float sgw = (pw > 0.f) ? 1.f : ((pw < 0.f) ? -1.f : 0.f);
    float sgh = (ph > 0.f) ? 1.f : ((ph < 0.f) ? -1.f : 0.f);
    float dw = __builtin_amdgcn_sqrtf(tw) - sgw * __builtin_amdgcn_sqrtf(fabsf(pw) + 1e-6f);
    float dh = __builtin_amdgcn_sqrtf(th) - sgh * __builtin_amdgcn_sqrtf(fabsf(ph) + 1e-6f);
    float wh = dw * dw + dh * dh;
    float dob = piou - conf;

    return obj * (5.f * (xy + wh) + dob * dob + cl) + (1.f - obj) * (0.5f * conf * conf);
}

// Direct-streaming: one cell per thread per grid-stride iteration.
// __launch_bounds__(256,4) caps VGPR at 128 -> 4 waves/SIMD = 16 waves/CU.
__global__ __launch_bounds__(TPB, 4) void yolo_main(
    const float* __restrict__ yt, const float* __restrict__ yp,
    float* __restrict__ partial, int ncells) {
    __shared__ float wsum[TPB / 64];

    const int tid = threadIdx.x;
    const long stride = (long)gridDim.x * TPB;

    float acc = 0.f;
    for (long cell = (long)blockIdx.x * TPB + tid; cell < ncells; cell += stride) {
        const float* tf = yt + cell * CH;
        const float* pf = yp + cell * CH;
        acc += cell_loss(tf, pf);
    }

    // wave reduction (64-wide), then cross-wave via LDS, plain store per block
#pragma unroll
    for (int off = 32; off > 0; off >>= 1)
        acc += __shfl_down(acc, off, 64);
    if ((tid & 63) == 0) wsum[tid >> 6] = acc;
    __syncthreads();
    if (tid == 0) {
        float s = 0.f;
#pragma unroll
        for (int w = 0; w < TPB / 64; ++w) s += wsum[w];
        partial[blockIdx.x] = s;
    }
}

__global__ __launch_bounds__(1024) void reduce_partials(
    const float* __restrict__ partial, float* __restrict__ out, int n) {
    __shared__ float ws[16];
    const int tid = threadIdx.x;
    float v = 0.f;
    for (int i = tid; i < n; i += 1024) v += partial[i];
#pragma unroll
    for (int off = 32; off > 0; off >>= 1)
        v += __shfl_down(v, off, 64);
    if ((tid & 63) == 0) ws[tid >> 6] = v;
    __syncthreads();
    if (tid == 0) {
        float s = 0.f;
#pragma unroll
        for (int w = 0; w < 16; ++w) s += ws[w];
        out[0] = s;
    }
}

extern "C" void kernel_launch(void* const* d_in, const int* in_sizes, int n_in,
                              void* d_out, int out_size, void* d_ws, size_t ws_size,
                              hipStream_t stream) {
    const float* yt = (const float*)d_in[0];
    const float* yp = (const float*)d_in[1];
    float* partial = (float*)d_ws;
    float* out = (float*)d_out;

    const int ncells = in_sizes[0] / CH;   // 3,211,264 at bench shape

    yolo_main<<<NBLOCKS, TPB, 0, stream>>>(yt, yp, partial, ncells);
    reduce_partials<<<1, 1024, 0, stream>>>(partial, out, NBLOCKS);
}

// Round 7
// 141.773 us; speedup vs baseline: 1.2997x; 1.2997x over previous
//
#include <hip/hip_runtime.h>

#define NC 20
#define CH 30

constexpr int WAVE = 64;
constexpr int CELLS_PER_TILE = 64;                 // one cell per lane per tile
constexpr int TILE_V4 = CELLS_PER_TILE * CH / 4;   // 480 float4 chunks per array
constexpr int TILE_FLOATS = CELLS_PER_TILE * CH;   // 1920 floats per array
constexpr int LDS_FLOATS = 2 * TILE_FLOATS;        // both arrays: 3840 floats = 15,360 B/buffer
constexpr int NBLOCKS = 1280;                      // 5 blocks/CU x 30,720 B = 153,600 B LDS (fits!)

// Per-cell YOLOv1 loss (validated rounds 1-6, absmax 0.0). 8B-aligned inputs.
__device__ __forceinline__ float cell_loss(const float* __restrict__ tf,
                                           const float* __restrict__ pf) {
    const float2* t2 = (const float2*)tf;
    const float2* p2 = (const float2*)pf;

    float cl = 0.f;
#pragma unroll
    for (int c = 0; c < NC / 2; ++c) {
        float2 a = t2[c], b = p2[c];
        float d0 = a.x - b.x, d1 = a.y - b.y;
        cl = fmaf(d0, d0, cl);
        cl = fmaf(d1, d1, cl);
    }
    float2 v10 = t2[10], v11 = t2[11];
    float th = t2[12].x;
    float obj = v10.x, tx = v10.y, ty = v11.x, tw = v11.y;
    float2 q10 = p2[10], q11 = p2[11], q12 = p2[12], q13 = p2[13], q14 = p2[14];
    float conf0 = q10.x, px0 = q10.y, py0 = q11.x, pw0 = q11.y, ph0 = q12.x;
    float conf1 = q12.y, px1 = q13.x, py1 = q13.y, pw1 = q14.x, ph1 = q14.y;

    float t_x1 = tx - tw * 0.5f, t_x2 = tx + tw * 0.5f;
    float t_y1 = ty - th * 0.5f, t_y2 = ty + th * 0.5f;
    float ta = fabsf((t_x2 - t_x1) * (t_y2 - t_y1));

    float b_x1 = px0 - pw0 * 0.5f, b_x2 = px0 + pw0 * 0.5f;
    float b_y1 = py0 - ph0 * 0.5f, b_y2 = py0 + ph0 * 0.5f;
    float ix = fmaxf(fminf(t_x2, b_x2) - fmaxf(t_x1, b_x1), 0.f);
    float iy = fmaxf(fminf(t_y2, b_y2) - fmaxf(t_y1, b_y1), 0.f);
    float inter0 = ix * iy;
    float a0 = fabsf((b_x2 - b_x1) * (b_y2 - b_y1));
    float iou0 = inter0 * __builtin_amdgcn_rcpf(ta + a0 - inter0 + 1e-6f);

    float c_x1 = px1 - pw1 * 0.5f, c_x2 = px1 + pw1 * 0.5f;
    float c_y1 = py1 - ph1 * 0.5f, c_y2 = py1 + ph1 * 0.5f;
    float jx = fmaxf(fminf(t_x2, c_x2) - fmaxf(t_x1, c_x1), 0.f);
    float jy = fmaxf(fminf(t_y2, c_y2) - fmaxf(t_y1, c_y1), 0.f);
    float inter1 = jx * jy;
    float a1 = fabsf((c_x2 - c_x1) * (c_y2 - c_y1));
    float iou1 = inter1 * __builtin_amdgcn_rcpf(ta + a1 - inter1 + 1e-6f);

    bool sel1 = iou1 > iou0;
    float conf = sel1 ? conf1 : conf0;
    float piou = sel1 ? iou1 : iou0;
    float px = sel1 ? px1 : px0;
    float py = sel1 ? py1 : py0;
    float pw = sel1 ? pw1 : pw0;
    float ph = sel1 ? ph1 : ph0;

    float dx = tx - px, dy = ty - py;
    float xy = dx * dx + dy * dy;
    float sgw = (pw > 0.f) ? 1.f : ((pw < 0.f) ? -1.f : 0.f);
    float sgh = (ph > 0.f) ? 1.f : ((ph < 0.f) ? -1.f : 0.f);
    float dw = __builtin_amdgcn_sqrtf(tw) - sgw * __builtin_amdgcn_sqrtf(fabsf(pw) + 1e-6f);
    float dh = __builtin_amdgcn_sqrtf(th) - sgh * __builtin_amdgcn_sqrtf(fabsf(ph) + 1e-6f);
    float wh = dw * dw + dh * dh;
    float dob = piou - conf;

    return obj * (5.f * (xy + wh) + dob * dob + cl) + (1.f - obj) * (0.5f * conf * conf);
}

// Single-wave block, barrierless double-buffered streaming (R2 structure),
// both arrays staged as ONE contiguous 15-wave-load stream (zero padding):
//   loads 0-6 : y_true chunks  [0,448)
//   load  7   : lanes 0-31 y_true [448,480), lanes 32-63 y_pred [0,32)
//   loads 8-14: y_pred chunks [32,480)
// gll's LDS dest stays lane-linear; only the global src is lane-split (legal).
__global__ __launch_bounds__(WAVE) void yolo_main(
    const float* __restrict__ yt, const float* __restrict__ yp,
    float* __restrict__ partial, int ncells, int ntiles) {
    __shared__ float buf[2][LDS_FLOATS];

    const int lane = threadIdx.x;
    const long total_v4 = ((long)ncells * CH) / 4;
    const float4* gt = (const float4*)yt;
    const float4* gp = (const float4*)yp;

    const int b = blockIdx.x;
    const int tpb = ntiles / gridDim.x;
    const int rem = ntiles - tpb * gridDim.x;
    const int n = tpb + (b < rem ? 1 : 0);
    const int start = b * tpb + (b < rem ? b : rem);

    float acc = 0.f;

#define GLL(SRC, DSTF) __builtin_amdgcn_global_load_lds(                       \
        (const __attribute__((address_space(1))) void*)(SRC),                  \
        (__attribute__((address_space(3))) void*)(DSTF), 16, 0, 0)

#define STAGE(BUF, TILE) do {                                                  \
    long _b4 = (long)(TILE) * TILE_V4;                                         \
    if (_b4 + TILE_V4 <= total_v4) {                                           \
        const float4* _t = gt + _b4;                                           \
        const float4* _p = gp + _b4;                                           \
        float* _d = &buf[BUF][0];                                              \
        _Pragma("unroll")                                                      \
        for (int _i = 0; _i < 7; ++_i)                                         \
            GLL(_t + _i * WAVE + lane, _d + _i * WAVE * 4);                    \
        const float4* _s7 = (lane < 32) ? (_t + 448 + lane)                    \
                                        : (_p + (lane - 32));                  \
        GLL(_s7, _d + 7 * WAVE * 4);                                           \
        _Pragma("unroll")                                                      \
        for (int _i = 8; _i < 15; ++_i)                                        \
            GLL(_p + 32 + (_i - 8) * WAVE + lane, _d + _i * WAVE * 4);         \
    } else {                                                                   \
        /* general-shape tail: per-lane clamped, both arrays */                \
        float* _d = &buf[BUF][0];                                              \
        _Pragma("unroll")                                                      \
        for (int _i = 0; _i < 15; ++_i) {                                      \
            long _c = (long)_i * WAVE + lane;                                  \
            long _it = _b4 + _c;             /* y_true chunk */                \
            long _ip = _b4 + _c - TILE_V4;   /* y_pred chunk */                \
            if (_it >= total_v4) _it = total_v4 - 1;                           \
            if (_ip < 0) _ip = 0;                                              \
            if (_ip >= total_v4) _ip = total_v4 - 1;                           \
            const float4* _s = (_c < TILE_V4) ? (gt + _it) : (gp + _ip);       \
            GLL(_s, _d + _i * WAVE * 4);                                       \
        }                                                                      \
    }                                                                          \
} while (0)

    if (n > 0) STAGE(0, start);
    if (n > 1) STAGE(1, start + 1);

    for (int t = 0; t < n; ++t) {
        const int cur = t & 1;
        if (t + 1 < n) {
            // wait for tile t's 15 loads; tile t+1's 15 stay in flight
            asm volatile("s_waitcnt vmcnt(15)" ::: "memory");
        } else {
            asm volatile("s_waitcnt vmcnt(0)" ::: "memory");
        }
        __builtin_amdgcn_sched_barrier(0);

        const int cell = (start + t) * CELLS_PER_TILE + lane;
        if (cell < ncells)
            acc += cell_loss(&buf[cur][lane * CH],
                             &buf[cur][TILE_FLOATS + lane * CH]);

        if (t + 2 < n) {
            // all ds_reads of buf[cur] must have executed before gll overwrites it
            asm volatile("s_waitcnt lgkmcnt(0)" ::: "memory");
            __builtin_amdgcn_sched_barrier(0);
            STAGE(cur, start + t + 2);
        }
    }
#undef STAGE
#undef GLL

    // single-wave reduction, plain store (no atomics, no d_out zeroing needed)
#pragma unroll
    for (int off = 32; off > 0; off >>= 1)
        acc += __shfl_down(acc, off, 64);
    if (lane == 0) partial[b] = acc;
}

__global__ __launch_bounds__(1024) void reduce_partials(
    const float* __restrict__ partial, float* __restrict__ out, int n) {
    __shared__ float ws[16];
    const int tid = threadIdx.x;
    float v = 0.f;
    for (int i = tid; i < n; i += 1024) v += partial[i];
#pragma unroll
    for (int off = 32; off > 0; off >>= 1)
        v += __shfl_down(v, off, 64);
    if ((tid & 63) == 0) ws[tid >> 6] = v;
    __syncthreads();
    if (tid == 0) {
        float s = 0.f;
#pragma unroll
        for (int w = 0; w < 16; ++w) s += ws[w];
        out[0] = s;
    }
}

extern "C" void kernel_launch(void* const* d_in, const int* in_sizes, int n_in,
                              void* d_out, int out_size, void* d_ws, size_t ws_size,
                              hipStream_t stream) {
    const float* yt = (const float*)d_in[0];
    const float* yp = (const float*)d_in[1];
    float* partial = (float*)d_ws;
    float* out = (float*)d_out;

    const int ncells = in_sizes[0] / CH;                                // 3,211,264
    const int ntiles = (ncells + CELLS_PER_TILE - 1) / CELLS_PER_TILE;  // 50,176

    const int nb = NBLOCKS < ntiles ? NBLOCKS : ntiles;
    yolo_main<<<nb, WAVE, 0, stream>>>(yt, yp, partial, ncells, ntiles);
    reduce_partials<<<1, 1024, 0, stream>>>(partial, out, nb);
}

// Round 8
// 135.285 us; speedup vs baseline: 1.3621x; 1.0480x over previous
//
#include <hip/hip_runtime.h>

#define NC 20
#define CH 30

constexpr int WAVE = 64;
constexpr int CELLS_PER_TILE = 64;                 // one cell per lane per tile
constexpr int TILE_V4 = CELLS_PER_TILE * CH / 4;   // 480 float4 chunks per array
constexpr int WLOADS = 8;                          // 8 wave-loads (480 real + 32 clamped pad)
constexpr int LDS_FLOATS = WLOADS * WAVE * 4;      // 2048 floats = 8 KB per array per buffer
constexpr int NBLOCKS = 1024;                      // 4 blocks/CU x 32 KB LDS; 50,176/1024 = 49 exact

// Per-cell YOLOv1 loss (validated rounds 1-7, absmax 0.0). 8B-aligned inputs.
__device__ __forceinline__ float cell_loss(const float* __restrict__ tf,
                                           const float* __restrict__ pf) {
    const float2* t2 = (const float2*)tf;
    const float2* p2 = (const float2*)pf;

    float cl = 0.f;
#pragma unroll
    for (int c = 0; c < NC / 2; ++c) {
        float2 a = t2[c], b = p2[c];
        float d0 = a.x - b.x, d1 = a.y - b.y;
        cl = fmaf(d0, d0, cl);
        cl = fmaf(d1, d1, cl);
    }
    float2 v10 = t2[10], v11 = t2[11];
    float th = t2[12].x;
    float obj = v10.x, tx = v10.y, ty = v11.x, tw = v11.y;
    float2 q10 = p2[10], q11 = p2[11], q12 = p2[12], q13 = p2[13], q14 = p2[14];
    float conf0 = q10.x, px0 = q10.y, py0 = q11.x, pw0 = q11.y, ph0 = q12.x;
    float conf1 = q12.y, px1 = q13.x, py1 = q13.y, pw1 = q14.x, ph1 = q14.y;

    float t_x1 = tx - tw * 0.5f, t_x2 = tx + tw * 0.5f;
    float t_y1 = ty - th * 0.5f, t_y2 = ty + th * 0.5f;
    float ta = fabsf((t_x2 - t_x1) * (t_y2 - t_y1));

    float b_x1 = px0 - pw0 * 0.5f, b_x2 = px0 + pw0 * 0.5f;
    float b_y1 = py0 - ph0 * 0.5f, b_y2 = py0 + ph0 * 0.5f;
    float ix = fmaxf(fminf(t_x2, b_x2) - fmaxf(t_x1, b_x1), 0.f);
    float iy = fmaxf(fminf(t_y2, b_y2) - fmaxf(t_y1, b_y1), 0.f);
    float inter0 = ix * iy;
    float a0 = fabsf((b_x2 - b_x1) * (b_y2 - b_y1));
    float iou0 = inter0 * __builtin_amdgcn_rcpf(ta + a0 - inter0 + 1e-6f);

    float c_x1 = px1 - pw1 * 0.5f, c_x2 = px1 + pw1 * 0.5f;
    float c_y1 = py1 - ph1 * 0.5f, c_y2 = py1 + ph1 * 0.5f;
    float jx = fmaxf(fminf(t_x2, c_x2) - fmaxf(t_x1, c_x1), 0.f);
    float jy = fmaxf(fminf(t_y2, c_y2) - fmaxf(t_y1, c_y1), 0.f);
    float inter1 = jx * jy;
    float a1 = fabsf((c_x2 - c_x1) * (c_y2 - c_y1));
    float iou1 = inter1 * __builtin_amdgcn_rcpf(ta + a1 - inter1 + 1e-6f);

    bool sel1 = iou1 > iou0;
    float conf = sel1 ? conf1 : conf0;
    float piou = sel1 ? iou1 : iou0;
    float px = sel1 ? px1 : px0;
    float py = sel1 ? py1 : py0;
    float pw = sel1 ? pw1 : pw0;
    float ph = sel1 ? ph1 : ph0;

    float dx = tx - px, dy = ty - py;
    float xy = dx * dx + dy * dy;
    float sgw = (pw > 0.f) ? 1.f : ((pw < 0.f) ? -1.f : 0.f);
    float sgh = (ph > 0.f) ? 1.f : ((ph < 0.f) ? -1.f : 0.f);
    float dw = __builtin_amdgcn_sqrtf(tw) - sgw * __builtin_amdgcn_sqrtf(fabsf(pw) + 1e-6f);
    float dh = __builtin_amdgcn_sqrtf(th) - sgh * __builtin_amdgcn_sqrtf(fabsf(ph) + 1e-6f);
    float wh = dw * dw + dh * dh;
    float dob = piou - conf;

    return obj * (5.f * (xy + wh) + dob * dob + cl) + (1.f - obj) * (0.5f * conf * conf);
}

// R2 structure: single-wave block, barrierless double-buffered streaming.
// Steady state: next tile's 16 loads stay in flight through each compute phase.
// STAGE fast path: wave-uniform bounds check, per-lane base computed once,
// immediate offsets folded into the 16 global_load_lds.
__global__ __launch_bounds__(WAVE) void yolo_main(
    const float* __restrict__ yt, const float* __restrict__ yp,
    float* __restrict__ partial, int ncells, int ntiles) {
    __shared__ float st[2][LDS_FLOATS];
    __shared__ float sp[2][LDS_FLOATS];

    const int lane = threadIdx.x;
    const long total_v4 = ((long)ncells * CH) / 4;
    const float4* gt = (const float4*)yt;
    const float4* gp = (const float4*)yp;

    const int b = blockIdx.x;
    const int tpb = ntiles / gridDim.x;
    const int rem = ntiles - tpb * gridDim.x;
    const int n = tpb + (b < rem ? 1 : 0);
    const int start = b * tpb + (b < rem ? b : rem);

    float acc = 0.f;

    // 8 wave-loads per array (480 real + 32 pad chunks; pad reads the next
    // tile's head -> L2 hit, ~0 extra HBM; LDS pad never read).
#define GLL(SRC, DSTF) __builtin_amdgcn_global_load_lds(                       \
        (const __attribute__((address_space(1))) void*)(SRC),                  \
        (__attribute__((address_space(3))) void*)(DSTF), 16, 0, 0)

#define STAGE(BUF, TILE) do {                                                  \
    long _base = (long)(TILE) * TILE_V4;                                       \
    if (_base + WLOADS * WAVE <= total_v4) {                                   \
        const float4* _t = gt + _base + lane;                                  \
        const float4* _p = gp + _base + lane;                                  \
        _Pragma("unroll")                                                      \
        for (int _i = 0; _i < WLOADS; ++_i) {                                  \
            GLL(_t + _i * WAVE, &st[BUF][_i * WAVE * 4]);                      \
            GLL(_p + _i * WAVE, &sp[BUF][_i * WAVE * 4]);                      \
        }                                                                      \
    } else {                                                                   \
        _Pragma("unroll")                                                      \
        for (int _i = 0; _i < WLOADS; ++_i) {                                  \
            long _idx = _base + _i * WAVE + lane;                              \
            if (_idx >= total_v4) _idx = total_v4 - 1;                         \
            GLL(gt + _idx, &st[BUF][_i * WAVE * 4]);                           \
            GLL(gp + _idx, &sp[BUF][_i * WAVE * 4]);                           \
        }                                                                      \
    }                                                                          \
} while (0)

    if (n > 0) STAGE(0, start);
    if (n > 1) STAGE(1, start + 1);

    for (int t = 0; t < n; ++t) {
        const int cur = t & 1;
        if (t + 1 < n) {
            // wait for tile t only; tile t+1's 16 loads stay in flight
            asm volatile("s_waitcnt vmcnt(16)" ::: "memory");
        } else {
            asm volatile("s_waitcnt vmcnt(0)" ::: "memory");
        }
        __builtin_amdgcn_sched_barrier(0);

        const int cell = (start + t) * CELLS_PER_TILE + lane;
        if (cell < ncells)
            acc += cell_loss(&st[cur][lane * CH], &sp[cur][lane * CH]);

        if (t + 2 < n) {
            // all ds_reads of buf[cur] must have executed before gll overwrites it
            asm volatile("s_waitcnt lgkmcnt(0)" ::: "memory");
            __builtin_amdgcn_sched_barrier(0);
            STAGE(cur, start + t + 2);
        }
    }
#undef STAGE
#undef GLL

    // single-wave reduction, plain store (no atomics, no d_out zeroing needed)
#pragma unroll
    for (int off = 32; off > 0; off >>= 1)
        acc += __shfl_down(acc, off, 64);
    if (lane == 0) partial[b] = acc;
}

__global__ __launch_bounds__(1024) void reduce_partials(
    const float* __restrict__ partial, float* __restrict__ out, int n) {
    __shared__ float ws[16];
    const int tid = threadIdx.x;
    float v = 0.f;
    for (int i = tid; i < n; i += 1024) v += partial[i];
#pragma unroll
    for (int off = 32; off > 0; off >>= 1)
        v += __shfl_down(v, off, 64);
    if ((tid & 63) == 0) ws[tid >> 6] = v;
    __syncthreads();
    if (tid == 0) {
        float s = 0.f;
#pragma unroll
        for (int w = 0; w < 16; ++w) s += ws[w];
        out[0] = s;
    }
}

extern "C" void kernel_launch(void* const* d_in, const int* in_sizes, int n_in,
                              void* d_out, int out_size, void* d_ws, size_t ws_size,
                              hipStream_t stream) {
    const float* yt = (const float*)d_in[0];
    const float* yp = (const float*)d_in[1];
    float* partial = (float*)d_ws;
    float* out = (float*)d_out;

    const int ncells = in_sizes[0] / CH;                                // 3,211,264
    const int ntiles = (ncells + CELLS_PER_TILE - 1) / CELLS_PER_TILE;  // 50,176

    const int nb = NBLOCKS < ntiles ? NBLOCKS : ntiles;
    yolo_main<<<nb, WAVE, 0, stream>>>(yt, yp, partial, ncells, ntiles);
    reduce_partials<<<1, 1024, 0, stream>>>(partial, out, nb);
}